// Round 1
// baseline (1078.622 us; speedup 1.0000x reference)
//
#include <hip/hip_runtime.h>
#include <hip/hip_bf16.h>

#define N_TOK 8192
#define D_IN  2048
#define D_OUT 8192
#define NEXP  8
#define BM    128
#define BN    128
#define BK    64
#define MAX_TILES 72

// ws layout (int units):
// [0]              num_tiles
// [8   .. 8+72)    tile_expert
// [96  .. 96+72)   tile_row_start
// [192 .. 192+72)  tile_rows
// [512 .. 512+N)   order (token ids grouped by expert)

typedef float  f32x4  __attribute__((ext_vector_type(4)));
typedef __bf16 bf16x8 __attribute__((ext_vector_type(8)));
typedef float  fx4    __attribute__((ext_vector_type(4)));

__global__ void SwitchLinear_setup_kernel(const int* __restrict__ idx,
                                          int* __restrict__ ws) {
    __shared__ int cnt[NEXP], cur[NEXP];
    int t = threadIdx.x;
    if (t < NEXP) cnt[t] = 0;
    __syncthreads();
    for (int i = t; i < N_TOK; i += 256) atomicAdd(&cnt[idx[i]], 1);
    __syncthreads();
    if (t == 0) {
        int o = 0, nt = 0;
        for (int e = 0; e < NEXP; ++e) {
            cur[e] = o;
            int c = cnt[e];
            for (int r = 0; r < c; r += BM) {
                ws[8 + nt]   = e;
                ws[96 + nt]  = o + r;
                ws[192 + nt] = (c - r < BM) ? (c - r) : BM;
                ++nt;
            }
            o += c;
        }
        ws[0] = nt;
    }
    __syncthreads();
    for (int i = t; i < N_TOK; i += 256) {
        int p = atomicAdd(&cur[idx[i]], 1);
        ws[512 + p] = i;
    }
}

// swizzled LDS byte offsets
__device__ __forceinline__ int a_byte(int r, int kbyte) {
    return r * 128 + (kbyte ^ ((r & 7) << 4));
}
__device__ __forceinline__ int b_byte(int n, int kbyte) {
    int slot = (n ^ (n >> 2)) & 7;
    return n * 128 + (kbyte ^ (slot << 4));
}

__global__ __launch_bounds__(256, 2) void SwitchLinear_gemm_kernel(
    const float* __restrict__ x, const float* __restrict__ w,
    const int* __restrict__ ws, float* __restrict__ out) {
    const int nt = ws[0];
    const int tx = blockIdx.x;
    if (tx >= nt) return;
    const int e    = ws[8 + tx];
    const int rs   = ws[96 + tx];
    const int rows = ws[192 + tx];
    const int col0 = blockIdx.y * BN;

    __shared__ __align__(16) unsigned short As[BM * BK]; // [row][k] bf16, swizzled
    __shared__ __align__(16) unsigned short Bs[BN * BK]; // [n][k] bf16 (W^T), swizzled
    __shared__ int ord[BM];

    const int t = threadIdx.x;
    if (t < BM) {
        int r = (t < rows) ? (rs + t) : rs;
        ord[t] = ws[512 + r];
    }
    __syncthreads();

    // --- A staging plan: thread covers rows (t>>4)+16i, float4-chunk kq=t&15
    const int kq = t & 15;
    const float* pA[8];
    int rowA[8];
#pragma unroll
    for (int i = 0; i < 8; ++i) {
        int r = (t >> 4) + 16 * i;
        rowA[i] = r;
        pA[i] = x + (long)ord[r] * D_IN + kq * 4;
    }
    // --- B staging plan: u = t + 256*i -> kg = u>>5 (16 groups of 4 k-rows), q = u&31
    const float* pB[2];
    int nB[2], kbB[2];
#pragma unroll
    for (int i = 0; i < 2; ++i) {
        int u = t + 256 * i;
        int kg = u >> 5, q = u & 31;
        kbB[i] = kg * 4;
        nB[i]  = q * 4;
        pB[i]  = w + (long)e * D_IN * D_OUT + (long)(kg * 4) * D_OUT + col0 + q * 4;
    }

    const int lane = t & 63;
    const int wid  = t >> 6;
    const int wr = wid >> 1, wc = wid & 1;
    const int lm = lane & 15, lk = lane >> 4;

    f32x4 acc[4][4];
#pragma unroll
    for (int i = 0; i < 4; ++i)
#pragma unroll
        for (int j = 0; j < 4; ++j) acc[i][j] = (f32x4){0.f, 0.f, 0.f, 0.f};

    for (int k0 = 0; k0 < D_IN; k0 += BK) {
        // ---- stage A: x rows -> bf16 LDS
#pragma unroll
        for (int i = 0; i < 8; ++i) {
            fx4 v = *(const fx4*)(pA[i] + k0);
            union { __bf16 h[4]; uint2 u; } c;
            c.h[0] = (__bf16)v[0]; c.h[1] = (__bf16)v[1];
            c.h[2] = (__bf16)v[2]; c.h[3] = (__bf16)v[3];
            int r = rowA[i];
            *(uint2*)((char*)As + a_byte(r, kq * 8)) = c.u;
        }
        // ---- stage B: W[k][n] -> W^T in LDS (register 4x4 transpose)
#pragma unroll
        for (int i = 0; i < 2; ++i) {
            const float* p = pB[i] + (long)k0 * D_OUT;
            fx4 r0 = *(const fx4*)(p);
            fx4 r1 = *(const fx4*)(p + D_OUT);
            fx4 r2 = *(const fx4*)(p + 2 * D_OUT);
            fx4 r3 = *(const fx4*)(p + 3 * D_OUT);
#pragma unroll
            for (int j = 0; j < 4; ++j) {
                int n = nB[i] + j;
                union { __bf16 h[4]; uint2 u; } c;
                c.h[0] = (__bf16)r0[j]; c.h[1] = (__bf16)r1[j];
                c.h[2] = (__bf16)r2[j]; c.h[3] = (__bf16)r3[j];
                *(uint2*)((char*)Bs + b_byte(n, kbB[i] * 2)) = c.u;
            }
        }
        __syncthreads();
        // ---- MFMA
#pragma unroll
        for (int ks = 0; ks < 2; ++ks) {
            bf16x8 a[4], b[4];
            const int kbyte = ks * 64 + lk * 16;
#pragma unroll
            for (int mi = 0; mi < 4; ++mi) {
                int r = wr * 64 + mi * 16 + lm;
                a[mi] = *(const bf16x8*)((const char*)As + a_byte(r, kbyte));
            }
#pragma unroll
            for (int ni = 0; ni < 4; ++ni) {
                int n = wc * 64 + ni * 16 + lm;
                b[ni] = *(const bf16x8*)((const char*)Bs + b_byte(n, kbyte));
            }
#pragma unroll
            for (int mi = 0; mi < 4; ++mi)
#pragma unroll
                for (int ni = 0; ni < 4; ++ni)
                    acc[mi][ni] = __builtin_amdgcn_mfma_f32_16x16x32_bf16(
                        a[mi], b[ni], acc[mi][ni], 0, 0, 0);
        }
        __syncthreads();
    }

    // ---- epilogue: C/D layout col=lane&15, row=(lane>>4)*4+reg
#pragma unroll
    for (int mi = 0; mi < 4; ++mi) {
#pragma unroll
        for (int j = 0; j < 4; ++j) {
            int rl = wr * 64 + mi * 16 + lk * 4 + j;
            if (rl < rows) {
                int token = ord[rl];
                float* po = out + (long)token * D_OUT + col0 + wc * 64 + lm;
#pragma unroll
                for (int ni = 0; ni < 4; ++ni) po[ni * 16] = acc[mi][ni][j];
            }
        }
    }
}

extern "C" void kernel_launch(void* const* d_in, const int* in_sizes, int n_in,
                              void* d_out, int out_size, void* d_ws, size_t ws_size,
                              hipStream_t stream) {
    const float* x   = (const float*)d_in[0];
    const float* w   = (const float*)d_in[1];
    const int*   idx = (const int*)d_in[2];
    float* out = (float*)d_out;
    int*   ws  = (int*)d_ws;

    SwitchLinear_setup_kernel<<<1, 256, 0, stream>>>(idx, ws);
    dim3 grid(MAX_TILES, D_OUT / BN);
    SwitchLinear_gemm_kernel<<<grid, 256, 0, stream>>>(x, w, ws, out);
}